// Round 1
// 411.400 us; speedup vs baseline: 1.2007x; 1.2007x over previous
//
#include <hip/hip_runtime.h>
#include <hip/hip_bf16.h>
#include <stdint.h>

#define B_  32
#define L_  128
#define D_  300
#define DP_ 304
#define H_  128
#define G_  512
#define E_  34
#define A_  36
#define M_  4096   // B*L
#define NC_ 106    // 34 ev + 36 base + 36 t2
#define NCP 112    // padded col count
#define CH_ 8      // scan chunk length
#define NCH 16     // chunks per sequence

__device__ __forceinline__ float sigf(float x){ return 1.0f / (1.0f + expf(-x)); }

// ---- P1: transpose W_ih into WT[d][k][n] (k-major, zero-padded k<304) ----
__global__ void k_prep1(const float* __restrict__ wihf, const float* __restrict__ wihb,
                        float* __restrict__ WT){
    int k = blockIdx.x;            // 0..303
    int d = blockIdx.y;            // 0..1
    int n = threadIdx.x;           // 0..511
    const float* w = d ? wihb : wihf;
    WT[((size_t)d * DP_ + k) * G_ + n] = (k < D_) ? w[(size_t)n * D_ + k] : 0.0f;
}

// ---- P2: pack head weights WcatT[k][n] (256 x NCP) + bias vector ----
__global__ void k_prep2(const float* __restrict__ evw, const float* __restrict__ evb,
                        const float* __restrict__ argw, const float* __restrict__ argb,
                        float* __restrict__ WcatT, float* __restrict__ biasv){
    int k = blockIdx.x;            // 0..255
    int n = threadIdx.x;           // 0..127
    if (n >= NCP) return;          // guard: block 128 wide, row 112
    float v = 0.0f;
    if (n < E_)       v = evw[(size_t)n * 256 + k];
    else if (n < 70)  v = argw[(size_t)(n - 34) * 545 + k];
    else if (n < NC_) v = argw[(size_t)(n - 70) * 545 + 256 + k];
    WcatT[(size_t)k * NCP + n] = v;
    if (k == 0){
        float bv = 0.0f;
        if (n < E_) bv = evb[n];
        else if (n < 70) bv = argb[n - 34];
        biasv[n] = bv;
    }
}

// ---- G1: XW[d][m][n] = emb[ids[m]][:] . w_ih_d[n][:] + b_ih[n] + b_hh[n] ----
__launch_bounds__(512)
__global__ void k_gemm1(const int* __restrict__ ids, const float* __restrict__ emb,
                        const float* __restrict__ WT,
                        const float* __restrict__ bihf, const float* __restrict__ bhhf,
                        const float* __restrict__ bihb, const float* __restrict__ bhhb,
                        float* __restrict__ XW){
    __shared__ float xs[8][DP_];
    int d  = blockIdx.y;
    int m0 = blockIdx.x * 8;
    int tid = threadIdx.x;
    for (int idx = tid; idx < 8 * DP_; idx += 512){
        int r = idx / DP_, k = idx % DP_;
        int id = ids[m0 + r];
        xs[r][k] = (k < D_) ? emb[(size_t)id * D_ + k] : 0.0f;
    }
    __syncthreads();
    int n = tid;
    const float* wcol = WT + (size_t)d * DP_ * G_ + n;
    float acc[8] = {};
    for (int k = 0; k < D_; k++){
        float wv = wcol[(size_t)k * G_];
        #pragma unroll
        for (int r = 0; r < 8; r++) acc[r] += xs[r][k] * wv;
    }
    float bias = d ? (bihb[n] + bhhb[n]) : (bihf[n] + bhhf[n]);
    for (int r = 0; r < 8; r++)
        XW[((size_t)d * M_ + m0 + r) * G_ + n] = acc[r] + bias;
}

// ---- K3: LSTM recurrence. 64 blocks = (dir,b); 512 threads = one z-row each.
// Round-7 restructure (theory: 3850 cyc/step vs 512 cyc issue floor was
// per-step vmcnt barrier-drains + serial transcendentals):
//  (1) xw loaded in chunks of 8 steps into statically-indexed regs -> the
//      barrier's vmcnt(0) drain stalls once per 8 steps, not every step.
//  (2) gate nonlinearities applied in phase A by all 512 threads (each z-row
//      IS one gate; wave-uniform branch picks tanh for rows 256..383).
//      Phase B serial chain is now just c=F*c+I*G; h=O*tanh(c).
//  (3) h history buffered in LDS (64 steps x 128 x f32 = 32KB), bulk-flushed
//      twice -> no global store drain inside the step barriers.
// Numerically identical to round-6 kernel (same formulas, same fp order).
#define LOAD_CH(XR, CHI)                                                        \
{                                                                               \
    _Pragma("unroll")                                                           \
    for (int j = 0; j < 8; j++){                                                \
        int s_ = (CHI) * 8 + j;                                                 \
        int t_ = d ? (L_ - 1 - s_) : s_;                                        \
        XR[j] = xwn[(size_t)t_ * G_];                                           \
    }                                                                           \
}

#define CHUNK_BODY(XR, CHI)                                                     \
{                                                                               \
    _Pragma("unroll")                                                           \
    for (int j = 0; j < 8; j++){                                                \
        int s_ = (CHI) * 8 + j;                                                 \
        float z0 = 0.f, z1 = 0.f, z2 = 0.f, z3 = 0.f;                           \
        const float4* hc = (const float4*)hbuf;                                 \
        _Pragma("unroll")                                                       \
        for (int q = 0; q < 32; q++){                                           \
            float4 hv = hc[q];                                                  \
            z0 += wv[q].x * hv.x;                                               \
            z1 += wv[q].y * hv.y;                                               \
            z2 += wv[q].z * hv.z;                                               \
            z3 += wv[q].w * hv.w;                                               \
        }                                                                       \
        float z = XR[j] + ((z0 + z1) + (z2 + z3));                              \
        float v = gate_g ? tanhf(z) : sigf(z);                                  \
        zbuf[n] = v;                                                            \
        __syncthreads();                                                        \
        if (n < H_){                                                            \
            float Fv = zbuf[H_ + n], Gv = zbuf[2*H_ + n], Ov = zbuf[3*H_ + n];  \
            c = Fv * c + v * Gv;                                                \
            float h = Ov * tanhf(c);                                            \
            hbuf[n] = h;                                                        \
            hist[(size_t)(s_ & 63) * H_ + n] = h;                               \
        }                                                                       \
        __syncthreads();                                                        \
    }                                                                           \
}

#define FLUSH_HIST(BASE)                                                        \
{                                                                               \
    _Pragma("unroll")                                                           \
    for (int q = 0; q < 4; q++){                                                \
        int idx = n + q * 512;                                                  \
        int sl = idx >> 5, n4 = idx & 31;                                       \
        int t_ = d ? (L_ - 1 - ((BASE) + sl)) : ((BASE) + sl);                  \
        *(float4*)(Hid + ((size_t)b * L_ + t_) * 256 + d * H_ + n4 * 4) =       \
            hist4[(size_t)sl * 32 + n4];                                        \
    }                                                                           \
}

__launch_bounds__(512, 2)
__global__ void k_lstm(const float* __restrict__ XW, const float* __restrict__ whhf,
                       const float* __restrict__ whhb, float* __restrict__ Hid){
    __shared__ __align__(16) float hbuf[H_];
    __shared__ float zbuf[G_];
    __shared__ __align__(16) float hist[64 * H_];   // 32 KB h history
    float4* hist4 = (float4*)hist;
    int bid = blockIdx.x;
    int d = bid >> 5, b = bid & 31;
    int n = threadIdx.x;           // 0..511
    bool gate_g = ((n >> 7) == 2); // rows 256..383 = g gate (tanh); others sigmoid
    const float4* wr = (const float4*)((d ? whhb : whhf) + (size_t)n * H_);
    float4 wv[32];
    #pragma unroll
    for (int q = 0; q < 32; q++) wv[q] = wr[q];
    float c = 0.0f;
    if (n < H_) hbuf[n] = 0.0f;
    __syncthreads();
    const float* xwn = XW + ((size_t)d * M_ + (size_t)b * L_) * G_ + n;
    #pragma unroll 1
    for (int ch = 0; ch < 16; ch++){
        float xr[8];
        LOAD_CH(xr, ch)
        CHUNK_BODY(xr, ch)
        if (ch == 7) FLUSH_HIST(0)
    }
    FLUSH_HIST(64)
}

// ---- K4: heads. One block per m. cols: 0..33 ev, 34..69 base, 70..105 t2. ----
__launch_bounds__(128)
__global__ void k_heads2(const float* __restrict__ Hid, const float* __restrict__ WcatT,
                         const float* __restrict__ biasv,
                         float* __restrict__ out0, float* __restrict__ Base,
                         float* __restrict__ T2, int* __restrict__ Evcol){
    __shared__ float hs[256];
    __shared__ float evl[E_];
    int m = blockIdx.x;
    int tid = threadIdx.x;         // 0..127
    hs[tid]       = Hid[(size_t)m * 256 + tid];
    hs[tid + 128] = Hid[(size_t)m * 256 + 128 + tid];
    __syncthreads();
    float acc = 0.0f;
    if (tid < NC_){
        const float* wc = WcatT + tid;
        for (int k = 0; k < 256; k++) acc += hs[k] * wc[(size_t)k * NCP];
        acc += biasv[tid];
    }
    if (tid < E_){
        out0[(size_t)m * E_ + tid] = acc;   // fp32 output
        evl[tid] = acc;
    } else if (tid < 70){
        Base[(size_t)m * A_ + (tid - 34)] = acc;
    } else if (tid < NC_){
        T2[(size_t)m * A_ + (tid - 70)] = acc;
    }
    __syncthreads();
    if (tid == 0){                 // first-max argmax over E=34
        float best = evl[0]; int bi = 0;
        for (int e = 1; e < E_; e++){
            float v = evl[e];
            if (v > best){ best = v; bi = e; }
        }
        Evcol[m] = bi - 1;         // -1 => ev_pred==0 (no g update)
    }
}

// ---- K5a: serial state propagation only. Snapshots (bg, mask) every CH_ steps.
// No argout stores here — that's phase 2's job.
__launch_bounds__(128)
__global__ void k_scan1(const float* __restrict__ Base, const float* __restrict__ T2,
                        const int* __restrict__ Evcol, const float* __restrict__ argw,
                        float* __restrict__ Snap, uint64_t* __restrict__ MaskSnap){
    __shared__ float t2s[L_ * A_];
    __shared__ float wgs[33 * A_];
    __shared__ int   evc[L_];
    int b = blockIdx.x;
    int l = threadIdx.x;             // 0..127
    for (int idx = l; idx < L_ * A_; idx += 128)
        t2s[idx] = T2[(size_t)b * L_ * A_ + idx];
    for (int idx = l; idx < 33 * A_; idx += 128){
        int c = idx / A_, a = idx % A_;
        wgs[idx] = argw[(size_t)a * 545 + 512 + c];
    }
    evc[l] = Evcol[b * L_ + l];
    __syncthreads();
    float bg[A_];
    {
        const float* bp = Base + ((size_t)b * L_ + l) * A_;
        #pragma unroll
        for (int a = 0; a < A_; a++) bg[a] = bp[a];
    }
    uint64_t mask = 0;
    #pragma unroll 1
    for (int i = 0; i < L_; i++){
        if ((i & (CH_ - 1)) == 0){
            int ch = i >> 3;
            float* sp = Snap + (((size_t)b * NCH + ch) * L_ + l) * A_;
            #pragma unroll
            for (int a = 0; a < A_; a++) sp[a] = bg[a];
            MaskSnap[((size_t)b * NCH + ch) * L_ + l] = mask;
        }
        const float* tr = t2s + i * A_;
        float lg0 = bg[0] + tr[0];
        float m1  = bg[1] + tr[1];
        #pragma unroll
        for (int a = 2; a < A_; a++) m1 = fmaxf(m1, bg[a] + tr[a]);
        bool apos = m1 > lg0;
        int cc = evc[i];
        if (cc >= 0 && apos && !((mask >> cc) & 1ull)){
            mask |= 1ull << cc;
            const float* wc = wgs + cc * A_;
            #pragma unroll
            for (int a = 0; a < A_; a++) bg[a] += wc[a];
        }
    }
}

// ---- K5b: parallel replay of CH_-step chunks from snapshots; does all stores.
// Bit-exact same ops as k_scan1 => identical decisions, exact state continuity.
__launch_bounds__(128)
__global__ void k_scan2(const float* __restrict__ T2, const int* __restrict__ Evcol,
                        const float* __restrict__ argw,
                        const float* __restrict__ Snap, const uint64_t* __restrict__ MaskSnap,
                        float* __restrict__ argout){
    __shared__ float t2s[CH_ * A_];
    __shared__ float wgs[33 * A_];
    __shared__ int   evc[CH_];
    int ch = blockIdx.x;             // 0..15
    int b  = blockIdx.y;             // 0..31
    int l  = threadIdx.x;            // 0..127
    int i0 = ch * CH_;
    for (int idx = l; idx < CH_ * A_; idx += 128)
        t2s[idx] = T2[((size_t)b * L_ + i0) * A_ + idx];
    for (int idx = l; idx < 33 * A_; idx += 128){
        int c = idx / A_, a = idx % A_;
        wgs[idx] = argw[(size_t)a * 545 + 512 + c];
    }
    if (l < CH_) evc[l] = Evcol[b * L_ + i0 + l];
    __syncthreads();
    float bg[A_];
    {
        const float* sp = Snap + (((size_t)b * NCH + ch) * L_ + l) * A_;
        #pragma unroll
        for (int a = 0; a < A_; a++) bg[a] = sp[a];
    }
    uint64_t mask = MaskSnap[((size_t)b * NCH + ch) * L_ + l];
    #pragma unroll 1
    for (int s = 0; s < CH_; s++){
        int i = i0 + s;
        const float* tr = t2s + s * A_;
        float lg[A_];
        #pragma unroll
        for (int a = 0; a < A_; a++) lg[a] = bg[a] + tr[a];
        float m1 = lg[1];
        #pragma unroll
        for (int a = 2; a < A_; a++) m1 = fmaxf(m1, lg[a]);
        bool apos = m1 > lg[0];
        float* op = argout + (((size_t)b * L_ + i) * L_ + l) * A_;
        #pragma unroll
        for (int q = 0; q < 9; q++){
            float4 v; v.x = lg[4*q]; v.y = lg[4*q+1]; v.z = lg[4*q+2]; v.w = lg[4*q+3];
            *(float4*)(op + 4 * q) = v;
        }
        int cc = evc[s];
        if (cc >= 0 && apos && !((mask >> cc) & 1ull)){
            mask |= 1ull << cc;
            const float* wc = wgs + cc * A_;
            #pragma unroll
            for (int a = 0; a < A_; a++) bg[a] += wc[a];
        }
    }
}

extern "C" void kernel_launch(void* const* d_in, const int* in_sizes, int n_in,
                              void* d_out, int out_size, void* d_ws, size_t ws_size,
                              hipStream_t stream){
    const int*   ids  = (const int*)  d_in[0];
    const float* emb  = (const float*)d_in[1];
    const float* wihf = (const float*)d_in[2];
    const float* whhf = (const float*)d_in[3];
    const float* bihf = (const float*)d_in[4];
    const float* bhhf = (const float*)d_in[5];
    const float* wihb = (const float*)d_in[6];
    const float* whhb = (const float*)d_in[7];
    const float* bihb = (const float*)d_in[8];
    const float* bhhb = (const float*)d_in[9];
    const float* evw  = (const float*)d_in[10];
    const float* evb  = (const float*)d_in[11];
    const float* argw = (const float*)d_in[12];
    const float* argb = (const float*)d_in[13];

    float* out0   = (float*)d_out;                 // [B,L,E] fp32
    float* argout = out0 + (size_t)M_ * E_;        // [B,L,L,A] fp32

    char* w = (char*)d_ws;                          // ~23.5 MB total
    float* WT    = (float*)w; w += (size_t)2 * DP_ * G_ * 4;   // 1.24 MB
    float* XW    = (float*)w; w += (size_t)2 * M_ * G_ * 4;    // 16.78 MB
    float* Hid   = (float*)w; w += (size_t)M_ * 256 * 4;       // 4.19 MB
    float* WcatT = (float*)w; w += (size_t)256 * NCP * 4;
    float* biasv = (float*)w; w += (size_t)NCP * 4;
    float* Base  = (float*)w; w += (size_t)M_ * A_ * 4;
    float* T2    = (float*)w; w += (size_t)M_ * A_ * 4;
    int*   Evcol = (int*)w;   w += (size_t)M_ * 4;

    // Scan snapshots alias the XW region (dead after k_lstm):
    // Snap 9.44 MB + MaskSnap 0.5 MB < 16.78 MB.
    float*    Snap     = XW;
    uint64_t* MaskSnap = (uint64_t*)(XW + (size_t)B_ * NCH * L_ * A_);

    k_prep1<<<dim3(DP_, 2), 512, 0, stream>>>(wihf, wihb, WT);
    k_prep2<<<256, 128, 0, stream>>>(evw, evb, argw, argb, WcatT, biasv);
    k_gemm1<<<dim3(M_ / 8, 2), 512, 0, stream>>>(ids, emb, WT, bihf, bhhf, bihb, bhhb, XW);
    k_lstm<<<64, 512, 0, stream>>>(XW, whhf, whhb, Hid);
    k_heads2<<<M_, 128, 0, stream>>>(Hid, WcatT, biasv, out0, Base, T2, Evcol);
    k_scan1<<<B_, 128, 0, stream>>>(Base, T2, Evcol, argw, Snap, MaskSnap);
    k_scan2<<<dim3(NCH, B_), 128, 0, stream>>>(T2, Evcol, argw, Snap, MaskSnap, argout);
}